// Round 5
// baseline (2151.954 us; speedup 1.0000x reference)
//
#include <hip/hip_runtime.h>

#define DEV __device__ __forceinline__

typedef __attribute__((ext_vector_type(8))) short short8;
typedef __attribute__((ext_vector_type(4))) float f32x4;

DEV float fast_rcp(float x) { return __builtin_amdgcn_rcpf(x); }
DEV float sigm(float x) { return fast_rcp(1.0f + __expf(-x)); }
DEV float tanhf_fast(float x) { return 1.0f - 2.0f * fast_rcp(1.0f + __expf(2.0f * x)); }

DEV short f2bf(float f) {
    unsigned u = __float_as_uint(f);
    unsigned r = (u + 0x7FFFu + ((u >> 16) & 1u)) >> 16;
    return (short)r;
}
DEV float bf2f(short h) {
    return __uint_as_float(((unsigned)(unsigned short)h) << 16);
}
DEV void split1(float f, short& h, short& l) {
    h = f2bf(f);
    l = f2bf(f - bf2f(h));
}
DEV void split8(const float4& x0, const float4& x1, short8& h, short8& l) {
    float fv[8] = {x0.x, x0.y, x0.z, x0.w, x1.x, x1.y, x1.z, x1.w};
#pragma unroll
    for (int j = 0; j < 8; ++j) { short hh, ll; split1(fv[j], hh, ll); h[j] = hh; l[j] = ll; }
}
#define MFMA16 __builtin_amdgcn_mfma_f32_16x16x32_bf16
DEV f32x4 mfma3(const short8& ah, const short8& al, const short8& bh, const short8& bl, f32x4 acc) {
    acc = MFMA16(ah, bh, acc, 0, 0, 0);
    acc = MFMA16(al, bh, acc, 0, 0, 0);
    acc = MFMA16(ah, bl, acc, 0, 0, 0);
    return acc;
}

// ---------------------------------------------------------------------------
// Split-K 2-segment MFMA GEMM core (verified round 4).  A fp32 [128][K] and
// W fp32 [N][ldw] row-major, both split to bf16 hi/lo IN-REGISTER.
// Out Cp[chunk][m=128][n]; 256 thr = 4 waves; wave w owns rows w*32..+31.
// Grid slice = (N/32)*KS; KC % 32 == 0; segment boundary K1 % 32 == 0.
// ---------------------------------------------------------------------------
DEV void gemm_core(int bx,
                   const float* __restrict__ A1, int K1,
                   const float* __restrict__ W1, int ldw1,
                   const float* __restrict__ A2, int K2,
                   const float* __restrict__ W2, int ldw2,
                   float* __restrict__ Cp, int N, int KS, int KC)
{
    const int tid = threadIdx.x;
    const int chunk = bx % KS;
    const int n0 = (bx / KS) * 32;
    const int kbeg = chunk * KC;
    const int w = tid >> 6, lane = tid & 63;
    const int q = lane >> 4, r = lane & 15;
    const int m_base = w * 32;

    f32x4 acc[2][2];
#pragma unroll
    for (int mt = 0; mt < 2; ++mt)
#pragma unroll
        for (int nt = 0; nt < 2; ++nt)
            acc[mt][nt] = (f32x4){0.f, 0.f, 0.f, 0.f};

    auto load_frag = [&](int kg, float4 (&a)[2][2], float4 (&wv)[2][2]) {
        const float* A; const float* W; int lda, ldw, kc;
        if (kg < K1) { A = A1; W = W1; lda = K1; ldw = ldw1; kc = kg; }
        else         { A = A2; W = W2; lda = K2; ldw = ldw2; kc = kg - K1; }
#pragma unroll
        for (int mt = 0; mt < 2; ++mt) {
            const float* ap = A + (size_t)(m_base + mt * 16 + r) * lda + kc + q * 8;
            a[mt][0] = *(const float4*)ap;
            a[mt][1] = *(const float4*)(ap + 4);
        }
#pragma unroll
        for (int nt = 0; nt < 2; ++nt) {
            const float* wp = W + (size_t)(n0 + nt * 16 + r) * ldw + kc + q * 8;
            wv[nt][0] = *(const float4*)wp;
            wv[nt][1] = *(const float4*)(wp + 4);
        }
    };

    auto compute = [&](const float4 (&a)[2][2], const float4 (&wv)[2][2]) {
        short8 bh[2], bl[2];
#pragma unroll
        for (int nt = 0; nt < 2; ++nt) split8(wv[nt][0], wv[nt][1], bh[nt], bl[nt]);
#pragma unroll
        for (int mt = 0; mt < 2; ++mt) {
            short8 ah, al;
            split8(a[mt][0], a[mt][1], ah, al);
#pragma unroll
            for (int nt = 0; nt < 2; ++nt)
                acc[mt][nt] = mfma3(ah, al, bh[nt], bl[nt], acc[mt][nt]);
        }
    };

    float4 aA[2][2], aB[2][2], wA[2][2], wB[2][2];
    const int nsteps = KC >> 5;

    load_frag(kbeg, aA, wA);
    for (int s = 0; s + 1 < nsteps; ++s) {
        if (s & 1) { load_frag(kbeg + (s + 1) * 32, aA, wA); compute(aB, wB); }
        else       { load_frag(kbeg + (s + 1) * 32, aB, wB); compute(aA, wA); }
    }
    if ((nsteps - 1) & 1) compute(aB, wB);
    else                  compute(aA, wA);

    float* Co = Cp + (size_t)chunk * 128 * N;
#pragma unroll
    for (int mt = 0; mt < 2; ++mt)
#pragma unroll
        for (int nt = 0; nt < 2; ++nt)
#pragma unroll
            for (int i = 0; i < 4; ++i)
                Co[(size_t)(m_base + mt * 16 + q * 4 + i) * N + n0 + nt * 16 + r] = acc[mt][nt][i];
}

// Release own partials, count in, return true for exactly the last block.
DEV bool arrive_last(int* cnt, int target)
{
    __shared__ int s_rank;
    __threadfence();
    __syncthreads();
    if (threadIdx.x == 0) s_rank = atomicAdd(cnt, 1);
    __syncthreads();
    if (s_rank == target - 1) { __threadfence(); return true; }
    return false;
}

// ---------------------------------------------------------------------------
// GEMM + fused reduce(+bias,+tanh) epilogue via per-n-tile counter.
// ---------------------------------------------------------------------------
__global__ __launch_bounds__(256) void gemm_fc_kernel(
    const float* __restrict__ A1, int K1, const float* __restrict__ W1, int ldw1,
    const float* __restrict__ A2, int K2, const float* __restrict__ W2, int ldw2,
    float* __restrict__ Cp, int N, int KS, int KC,
    const float* __restrict__ bias, float* __restrict__ outp, int act, int* cnt)
{
    gemm_core(blockIdx.x, A1, K1, W1, ldw1, A2, K2, W2, ldw2, Cp, N, KS, KC);
    const int ntile = blockIdx.x / KS;
    if (arrive_last(&cnt[ntile], KS)) {
        const int tid = threadIdx.x;
        const int c = tid & 31, mrow = tid >> 5;
        const int n0 = ntile * 32;
        const size_t MN = (size_t)128 * N;
        for (int p = 0; p < 16; ++p) {
            int m = p * 8 + mrow;
            int n = n0 + c;
            float v = bias ? bias[n] : 0.f;
            for (int s = 0; s < KS; ++s) v += Cp[(size_t)s * MN + (size_t)m * N + n];
            if (act) v = tanhf_fast(v);
            outp[(size_t)m * N + n] = v;
        }
    }
}

// ---------------------------------------------------------------------------
// GRU: gi GEMM (288 blocks, KS=12) + gh GEMM (192 blocks, KS=8) + fused gate.
// Counter per 32-col d-tile (8 tiles); contributors 3*12 + 3*8 = 60.
// ---------------------------------------------------------------------------
__global__ __launch_bounds__(256) void gemm_gru_kernel(
    const float* __restrict__ ctxv, const float* __restrict__ pout,
    const float* __restrict__ h_old,
    const float* __restrict__ wih, const float* __restrict__ whh,
    float* __restrict__ Pa, float* __restrict__ Pb,
    const float* __restrict__ bih, const float* __restrict__ bhh,
    float* __restrict__ h_new, int* cnt)
{
    int j;
    if (blockIdx.x < 288) {
        gemm_core(blockIdx.x, ctxv, 256, wih, 384, pout, 128, wih + 256, 384,
                  Pa, 768, 12, 32);
        j = (blockIdx.x / 12) & 7;
    } else {
        gemm_core(blockIdx.x - 288, h_old, 256, whh, 256, nullptr, 0, nullptr, 0,
                  Pb, 768, 8, 32);
        j = ((blockIdx.x - 288) / 8) & 7;
    }
    if (arrive_last(&cnt[j], 60)) {
        const int tid = threadIdx.x;
        const int c = tid & 31, mrow = tid >> 5;
        const size_t MN = (size_t)128 * 768;
        for (int p = 0; p < 16; ++p) {
            int m = p * 8 + mrow;
            int d = j * 32 + c;
            size_t base = (size_t)m * 768 + d;
            float ir = bih[d], iz = bih[256 + d], in = bih[512 + d];
            for (int s = 0; s < 12; ++s) {
                const float* pp = Pa + s * MN + base;
                ir += pp[0]; iz += pp[256]; in += pp[512];
            }
            float hr = bhh[d], hz = bhh[256 + d], hn = bhh[512 + d];
            for (int s = 0; s < 8; ++s) {
                const float* pp = Pb + s * MN + base;
                hr += pp[0]; hz += pp[256]; hn += pp[512];
            }
            float rr = sigm(ir + hr), zz = sigm(iz + hz);
            float nn = tanhf_fast(in + rr * hn);
            h_new[m * 256 + d] = (1.f - zz) * nn + zz * h_old[m * 256 + d];
        }
    }
}

// ---------------------------------------------------------------------------
// LSTM: side-0 GEMM (2-segment A/W, e.g. [x|h] or [prenet|x]) and optional
// side-1 GEMM (h-side) in one launch; fused gate epilogue.
// Partials: side-0 chunks [0,KS), side-1 chunks [KS,2KS).
// Counter per 32-col d-tile; contributors (4 gate n-tiles)*KS*(1 or 2 sides).
// x_old read through segmented view (d<split ? xa : xb); x_new = x_old + h2.
// ---------------------------------------------------------------------------
__global__ __launch_bounds__(256) void gemm_lstm_kernel(
    const float* __restrict__ A1, int K1, const float* __restrict__ W1, int ldw1,
    const float* __restrict__ A2, int K2, const float* __restrict__ W2, int ldw2,
    const float* __restrict__ Ah, int Kh, const float* __restrict__ Wh,
    float* __restrict__ P, int N, int KS, int KC0, int KC1,
    const float* __restrict__ bih, const float* __restrict__ bhh,
    const float* __restrict__ c_in,
    float* __restrict__ h_out, float* __restrict__ c_out,
    const float* __restrict__ xa, int sa,
    const float* __restrict__ xb, int sb, int split,
    float* __restrict__ x_new, int H, int* cnt)
{
    const int nb0 = (N / 32) * KS;
    const int hasH = (Ah != nullptr);
    const size_t MN = (size_t)128 * N;
    int ntile;
    if ((int)blockIdx.x < nb0) {
        gemm_core(blockIdx.x, A1, K1, W1, ldw1, A2, K2, W2, ldw2, P, N, KS, KC0);
        ntile = blockIdx.x / KS;
    } else {
        int bx2 = blockIdx.x - nb0;
        gemm_core(bx2, Ah, Kh, Wh, Kh, nullptr, 0, nullptr, 0,
                  P + (size_t)KS * MN, N, KS, KC1);
        ntile = bx2 / KS;
    }
    const int dtiles = H >> 5;
    const int j = ntile % dtiles;
    const int target = (hasH ? 8 : 4) * KS;
    const int nch = (hasH ? 2 : 1) * KS;
    if (arrive_last(&cnt[j], target)) {
        const int tid = threadIdx.x;
        const int c = tid & 31, mrow = tid >> 5;
        for (int p = 0; p < 16; ++p) {
            int m = p * 8 + mrow;
            int d = j * 32 + c;
            float gv[4];
#pragma unroll
            for (int g = 0; g < 4; ++g) {
                int gc = g * H + d;
                float v = bih[gc] + bhh[gc];
                for (int s = 0; s < nch; ++s)
                    v += P[(size_t)s * MN + (size_t)m * N + gc];
                gv[g] = v;
            }
            size_t o = (size_t)m * H + d;
            float c2 = sigm(gv[1]) * c_in[o] + sigm(gv[0]) * tanhf_fast(gv[2]);
            float h2 = sigm(gv[3]) * tanhf_fast(c2);
            h_out[o] = h2;
            c_out[o] = c2;
            float xo = (d < split) ? xa[(size_t)m * sa + d] : xb[(size_t)m * sb + d - split];
            x_new[o] = xo + h2;
        }
    }
}

// ---------------------------------------------------------------------------
// Fused LSA u-kernel (unchanged, harness-verified): conv(loc) -> bf16 MFMA
// L-projection -> tanh -> v-dot -> sigmoid(u).
// ---------------------------------------------------------------------------
__global__ __launch_bounds__(256) void attn_u_kernel(
    const float* __restrict__ esp, const float* __restrict__ pq,
    const float* __restrict__ Lw, const float* __restrict__ Lb,
    const float* __restrict__ vw, const float* __restrict__ cw,
    const float* __restrict__ cum, const float* __restrict__ prev,
    float* __restrict__ sig_out)
{
    const int b = blockIdx.x >> 4;
    const int t0 = (blockIdx.x & 15) << 6;
    const int tid = threadIdx.x;

    __shared__ float cum_s[94], prev_s[94];
    __shared__ float cw_s[2][32][33];
    __shared__ short conv_bf[64 * 32];
    __shared__ short lw_bf[256 * 32];
    __shared__ float pq_s[256], vw_s[256];

    if (tid < 94) {
        int ti = t0 - 15 + tid;
        cum_s[tid] = (ti >= 0 && ti < 1024) ? cum[b * 1024 + ti] : 0.f;
    } else if (tid >= 128 && tid < 222) {
        int i = tid - 128;
        int ti = t0 - 15 + i;
        prev_s[i] = (ti >= 0 && ti < 1024) ? prev[b * 1024 + ti] : 0.f;
    }
    for (int i = tid; i < 2048; i += 256) {
        int which = i >> 10, c = (i >> 5) & 31, k = i & 31;
        cw_s[which][c][k] = (k < 31) ? cw[(c * 2 + which) * 31 + k] : 0.f;
    }
    {   // L_w fp32 -> bf16 into LDS
        const float4* src = (const float4*)Lw;
#pragma unroll
        for (int k = 0; k < 8; ++k) {
            float4 v = src[tid + k * 256];
            int base = (tid + k * 256) * 4;
            lw_bf[base + 0] = f2bf(v.x);
            lw_bf[base + 1] = f2bf(v.y);
            lw_bf[base + 2] = f2bf(v.z);
            lw_bf[base + 3] = f2bf(v.w);
        }
    }
    pq_s[tid] = pq[b * 256 + tid] + Lb[tid];
    vw_s[tid] = vw[tid];
    __syncthreads();

    {
        int c = tid & 31, t8 = (tid >> 5) << 3;
        float a[8] = {0.f, 0.f, 0.f, 0.f, 0.f, 0.f, 0.f, 0.f};
        for (int k = 0; k < 31; ++k) {
            float w0 = cw_s[0][c][k], w1 = cw_s[1][c][k];
#pragma unroll
            for (int j = 0; j < 8; ++j)
                a[j] += w0 * cum_s[t8 + j + k] + w1 * prev_s[t8 + j + k];
        }
#pragma unroll
        for (int j = 0; j < 8; ++j) conv_bf[(t8 + j) * 32 + c] = f2bf(a[j]);
    }
    __syncthreads();

    const int lane = tid & 63, w = tid >> 6;
    const int q = lane >> 4, c16 = lane & 15;
    const int myt = t0 + w * 16 + c16;

    short8 bfrag = *(const short8*)&conv_bf[(w * 16 + c16) * 32 + q * 8];
    const float* er = esp + ((size_t)(b * 1024 + myt) << 8);

    float s = 0.f;
#pragma unroll
    for (int dt = 0; dt < 16; ++dt) {
        short8 afrag = *(const short8*)&lw_bf[(dt * 16 + c16) * 32 + q * 8];
        f32x4 acc = {0.f, 0.f, 0.f, 0.f};
        acc = MFMA16(afrag, bfrag, acc, 0, 0, 0);
        const int d0 = dt * 16 + q * 4;
        float4 e   = *(const float4*)(er + d0);
        float4 pqv = *(const float4*)&pq_s[d0];
        float4 vwv = *(const float4*)&vw_s[d0];
        s += tanhf_fast(pqv.x + e.x + acc[0]) * vwv.x;
        s += tanhf_fast(pqv.y + e.y + acc[1]) * vwv.y;
        s += tanhf_fast(pqv.z + e.z + acc[2]) * vwv.z;
        s += tanhf_fast(pqv.w + e.w + acc[3]) * vwv.w;
    }
    s += __shfl_xor(s, 16);
    s += __shfl_xor(s, 32);
    if (lane < 16)
        sig_out[b * 1024 + t0 + w * 16 + lane] = sigm(s);
}

// ---------------------------------------------------------------------------
// attn_ctx + fused normalization.  8 blocks per b accumulate unnormalized
// context (atomicAdd) and partial sig-sums; the last block per b normalizes
// ctx and writes scores / cum_new.
// ---------------------------------------------------------------------------
__global__ __launch_bounds__(256) void attn_ctx_kernel(
    const float* __restrict__ sig, const float* __restrict__ es,
    const float* __restrict__ cum,
    float* __restrict__ ctx, float* __restrict__ scores,
    float* __restrict__ cum_new, float* __restrict__ ssum, int* cnt)
{
    __shared__ float sc_s[128];
    const int b = blockIdx.x >> 3;
    const int tbase = (blockIdx.x & 7) * 128;
    const int tid = threadIdx.x;
    if (tid < 128) sc_s[tid] = sig[b * 1024 + tbase + tid];
    __syncthreads();

    // partial sum of sig for this t-chunk
    float v = (tid < 128) ? sc_s[tid] : 0.f;
#pragma unroll
    for (int off = 1; off < 64; off <<= 1) v += __shfl_xor(v, off);
    if (tid < 128 && (tid & 63) == 0) atomicAdd(&ssum[b], v);

    // unnormalized context accumulation
    float a = 0.f;
    const float* ep = es + ((size_t)(b * 1024 + tbase)) * 256 + tid;
#pragma unroll 4
    for (int tt = 0; tt < 128; ++tt)
        a += sc_s[tt] * ep[(size_t)tt * 256];
    atomicAdd(&ctx[b * 256 + tid], a);

    if (arrive_last(&cnt[b], 8)) {
        float inv = fast_rcp(ssum[b]);
        ctx[b * 256 + tid] *= inv;
#pragma unroll
        for (int p = 0; p < 4; ++p) {
            int i = p * 256 + tid;
            float sc = sig[b * 1024 + i] * inv;
            scores[b * 1024 + i] = sc;
            cum_new[b * 1024 + i] = cum[b * 1024 + i] + sc;
        }
    }
}

// ---------------------------------------------------------------------------
__global__ void init_kernel(int* __restrict__ cnt, float* __restrict__ ssum,
                            float* __restrict__ ctx)
{
    int i = blockIdx.x * 256 + threadIdx.x;
    if (i < 512) cnt[i] = 0;
    if (i < 128) ssum[i] = 0.f;
    if (i < 32768) ctx[i] = 0.f;
}

// ---------------------------------------------------------------------------
__global__ void stop_kernel(const float* __restrict__ res, const float* __restrict__ sw,
                            const float* __restrict__ sb, float* __restrict__ stop)
{
    int m = blockIdx.x, lane = threadIdx.x;
    float s = 0.f;
    for (int k = lane; k < 640; k += 64) s += res[m * 640 + k] * sw[k];
#pragma unroll
    for (int off = 1; off < 64; off <<= 1) s += __shfl_xor(s, off);
    if (lane == 0) stop[m] = sigm(s + sb[0]);
}

// ---------------------------------------------------------------------------
extern "C" void kernel_launch(void* const* d_in, const int* in_sizes, int n_in,
                              void* d_out, int out_size, void* d_ws, size_t ws_size,
                              hipStream_t stream)
{
    const float* encoder_seq      = (const float*)d_in[0];
    const float* encoder_seq_proj = (const float*)d_in[1];
    const float* prenet_in        = (const float*)d_in[2];
    const float* attn_hidden      = (const float*)d_in[3];
    const float* rnn1_h  = (const float*)d_in[4];
    const float* rnn1_c  = (const float*)d_in[5];
    const float* rnn2_h  = (const float*)d_in[6];
    const float* rnn2_c  = (const float*)d_in[7];
    const float* res_h   = (const float*)d_in[8];
    const float* res_c   = (const float*)d_in[9];
    const float* context_vec = (const float*)d_in[10];
    const float* cumulative  = (const float*)d_in[11];
    const float* attn_prev   = (const float*)d_in[12];
    const float* fc1_w = (const float*)d_in[13];
    const float* fc1_b = (const float*)d_in[14];
    const float* fc2_w = (const float*)d_in[15];
    const float* fc2_b = (const float*)d_in[16];
    const float* gru_wih = (const float*)d_in[17];
    const float* gru_whh = (const float*)d_in[18];
    const float* gru_bih = (const float*)d_in[19];
    const float* gru_bhh = (const float*)d_in[20];
    const float* conv_w = (const float*)d_in[21];
    const float* L_w = (const float*)d_in[22];
    const float* L_b = (const float*)d_in[23];
    const float* W_w = (const float*)d_in[24];
    const float* W_b = (const float*)d_in[25];
    const float* v_w = (const float*)d_in[26];
    const float* ri_w = (const float*)d_in[27];
    const float* ri_b = (const float*)d_in[28];
    const float* r1_wih = (const float*)d_in[29];
    const float* r1_whh = (const float*)d_in[30];
    const float* r1_bih = (const float*)d_in[31];
    const float* r1_bhh = (const float*)d_in[32];
    const float* r2_wih = (const float*)d_in[33];
    const float* r2_whh = (const float*)d_in[34];
    const float* r2_bih = (const float*)d_in[35];
    const float* r2_bhh = (const float*)d_in[36];
    const float* res_wih = (const float*)d_in[37];
    const float* res_whh = (const float*)d_in[38];
    const float* res_bih = (const float*)d_in[39];
    const float* res_bhh = (const float*)d_in[40];
    const float* stop_w = (const float*)d_in[41];
    const float* stop_b = (const float*)d_in[42];

    float* ws  = (float*)d_ws;
    float* out = (float*)d_out;

    // workspace offsets (floats)
    const size_t OFF_P     = 0;        // fc1 out [128,256]
    const size_t OFF_POUT  = 32768;    // fc2 out [128,128]
    const size_t OFF_PQ    = 49152;    // [128,256]
    const size_t OFF_SIG   = 81920;    // [128,1024]
    const size_t OFF_X     = 212992;   // ri out [128,512]
    const size_t OFF_XB    = 278528;   // x + h1 [128,512]
    const size_t OFF_XC    = 344064;   // x + h1 + h2 [128,512]
    const size_t OFF_R0    = 409600;   // res ping [128,640]
    const size_t OFF_R1    = 491520;   // res pong [128,640]
    const size_t OFF_PART  = 573440;   // split-K partials (max 8*128*2560)
    const size_t OFF_PARTB = OFF_PART + (size_t)12 * 128 * 768;   // GRU gh partials
    const size_t OFF_CNT   = 3300000;  // counters (512 ints) + ssum (128 f)

    int*   cnt  = (int*)(ws + OFF_CNT);
    float* ssum = ws + OFF_CNT + 512;

    // counter slot bases
    const int CNT_FC1 = 0, CNT_FC2 = 8, CNT_GRU = 16, CNT_PQ = 24,
              CNT_RI = 32, CNT_L1 = 48, CNT_L2 = 64, CNT_RES = 80,
              CNT_ATT = 160;

    // output offsets (floats)
    const size_t O_COND   = 0;
    const size_t O_STOP   = 81920;
    const size_t O_SCORES = 82048;
    const size_t O_ATTNH  = 213120;
    const size_t O_H1     = 245888;
    const size_t O_C1     = 311424;
    const size_t O_H2     = 376960;
    const size_t O_C2     = 442496;
    const size_t O_HS     = 508032;
    const size_t O_CS     = 835712;
    const size_t O_CTX    = 1163392;
    const size_t O_CUM    = 1196160;

    // 1. init counters / ssum / ctx
    init_kernel<<<128, 256, 0, stream>>>(cnt, ssum, out + O_CTX);

    // 2. PreNet fc1: N=256, K=128, KS=4 (KC=32), fused reduce+tanh
    gemm_fc_kernel<<<32, 256, 0, stream>>>(
        prenet_in, 128, fc1_w, 128, nullptr, 0, nullptr, 0,
        ws + OFF_PART, 256, 4, 32, fc1_b, ws + OFF_P, 1, cnt + CNT_FC1);

    // 3. PreNet fc2: N=128, K=256, KS=8 (KC=32)
    gemm_fc_kernel<<<32, 256, 0, stream>>>(
        ws + OFF_P, 256, fc2_w, 256, nullptr, 0, nullptr, 0,
        ws + OFF_PART, 128, 8, 32, fc2_b, ws + OFF_POUT, 1, cnt + CNT_FC2);

    // 4. GRU: gi (288 blocks) + gh (192 blocks) + fused gate
    gemm_gru_kernel<<<480, 256, 0, stream>>>(
        context_vec, ws + OFF_POUT, attn_hidden, gru_wih, gru_whh,
        ws + OFF_PART, ws + OFF_PARTB,
        gru_bih, gru_bhh, out + O_ATTNH, cnt + CNT_GRU);

    // 5. pq: N=256, K=256, KS=8 (KC=32)
    gemm_fc_kernel<<<64, 256, 0, stream>>>(
        out + O_ATTNH, 256, W_w, 256, nullptr, 0, nullptr, 0,
        ws + OFF_PART, 256, 8, 32, W_b, ws + OFF_PQ, 0, cnt + CNT_PQ);

    // 6. attention u
    attn_u_kernel<<<2048, 256, 0, stream>>>(encoder_seq_proj, ws + OFF_PQ, L_w,
                                            L_b, v_w, conv_w, cumulative, attn_prev,
                                            ws + OFF_SIG);
    // 7. context + fused normalization / scores / cum_new
    attn_ctx_kernel<<<1024, 256, 0, stream>>>(
        ws + OFF_SIG, encoder_seq, cumulative,
        out + O_CTX, out + O_SCORES, out + O_CUM, ssum, cnt + CNT_ATT);

    // 8. x = [context | attn_h] @ ri_w^T + ri_b : N=512, K=256+256, KS=8 (KC=64)
    gemm_fc_kernel<<<128, 256, 0, stream>>>(
        out + O_CTX, 256, ri_w, 512,
        out + O_ATTNH, 256, ri_w + 256, 512,
        ws + OFF_PART, 512, 8, 64, ri_b, ws + OFF_X, 0, cnt + CNT_RI);

    // 9. LSTM 1: [x|h] 2-segment K=1024, KS=4 (KC=256), fused gate; XB = X + h1
    gemm_lstm_kernel<<<256, 256, 0, stream>>>(
        ws + OFF_X, 512, r1_wih, 512, rnn1_h, 512, r1_whh, 512,
        nullptr, 0, nullptr,
        ws + OFF_PART, 2048, 4, 256, 0,
        r1_bih, r1_bhh, rnn1_c, out + O_H1, out + O_C1,
        nullptr, 0, ws + OFF_X, 512, 0, ws + OFF_XB, 512, cnt + CNT_L1);

    // 10. LSTM 2: XC = XB + h2
    gemm_lstm_kernel<<<256, 256, 0, stream>>>(
        ws + OFF_XB, 512, r2_wih, 512, rnn2_h, 512, r2_whh, 512,
        nullptr, 0, nullptr,
        ws + OFF_PART, 2048, 4, 256, 0,
        r2_bih, r2_bhh, rnn2_c, out + O_H2, out + O_C2,
        nullptr, 0, ws + OFF_XB, 512, 0, ws + OFF_XC, 512, cnt + CNT_L2);

    // 11-14. Residual stack: x-side (2-seg for layer 0) + h-side + fused gate.
    for (int i = 0; i < 4; ++i) {
        const float* wih = res_wih + (size_t)i * 2560 * 640;
        const float* whh = res_whh + (size_t)i * 2560 * 640;
        const float* hA  = res_h + (size_t)i * 81920;
        const float* cA  = res_c + (size_t)i * 81920;
        const float *xa, *xb; int sa, sb, split;
        const float *A1, *A2, *W1, *W2; int K1, K2;
        if (i == 0) {
            A1 = prenet_in; K1 = 128; W1 = wih;
            A2 = ws + OFF_XC; K2 = 512; W2 = wih + 128;
            xa = prenet_in; sa = 128; xb = ws + OFF_XC; sb = 512; split = 128;
        } else {
            A1 = ws + ((i & 1) ? OFF_R0 : OFF_R1); K1 = 640; W1 = wih;
            A2 = nullptr; K2 = 0; W2 = nullptr;
            xa = nullptr; sa = 0; xb = A1; sb = 640; split = 0;
        }
        float* xnew = (i == 3) ? (out + O_COND) : (ws + ((i & 1) ? OFF_R1 : OFF_R0));
        gemm_lstm_kernel<<<640, 256, 0, stream>>>(
            A1, K1, W1, 640, A2, K2, W2, 640,
            hA, 640, whh,
            ws + OFF_PART, 2560, 4, 160, 160,
            res_bih + (size_t)i * 2560, res_bhh + (size_t)i * 2560,
            cA, out + O_HS + (size_t)i * 81920, out + O_CS + (size_t)i * 81920,
            xa, sa, xb, sb, split, xnew, 640, cnt + CNT_RES + 20 * i);
    }

    // 15. stop
    stop_kernel<<<128, 64, 0, stream>>>(out + O_COND, stop_w, stop_b, out + O_STOP);
}